// Round 5
// baseline (548.232 us; speedup 1.0000x reference)
//
#include <hip/hip_runtime.h>
#include <hip/hip_bf16.h>
#include <cstddef>
#include <cstdint>

// Problem constants
#define BB   2
#define NN   8192
#define CA   128
#define CS   384
#define CZ   16
#define HH   4
#define DD   32
#define NQW  32      // NQ
#define NKW  128     // NK
#define NBLK 3
#define WW   256     // N / NQ
#define MR   (BB*NN) // 16384 rows
#define HIDN 256     // 2*CA

typedef unsigned short u16;
typedef __attribute__((ext_vector_type(8))) short short8;
typedef __attribute__((ext_vector_type(4))) float floatx4;

__device__ __forceinline__ float sigmoidf_(float x) { return 1.f / (1.f + __expf(-x)); }

__device__ __forceinline__ u16 f2bf(float x) {
  unsigned u = __float_as_uint(x);
  unsigned r = (u + 0x7fffu + ((u >> 16) & 1u)) >> 16;
  return (u16)r;
}
__device__ __forceinline__ float bf2f(u16 u) {
  return __uint_as_float(((unsigned)u) << 16);
}

// async global->LDS, 16B per lane; lds base must be wave-uniform.
typedef const unsigned int __attribute__((address_space(1)))* gas_t;
typedef unsigned int __attribute__((address_space(3)))* las_t;
__device__ __forceinline__ void gload16(const u16* gp, u16* lds_wave_base) {
  __builtin_amdgcn_global_load_lds((gas_t)(const void*)gp, (las_t)(void*)lds_wave_base, 16, 0, 0);
}

// ---------------------------------------------------------------------------
// LayerNorm of s (C_S = 384), one wave per row -> bf16 out.
// ---------------------------------------------------------------------------
__global__ __launch_bounds__(256) void ln_s_kernel(const float* __restrict__ s,
                                                   u16* __restrict__ s_ln_bf) {
  int row  = blockIdx.x * 4 + (threadIdx.x >> 6);
  int lane = threadIdx.x & 63;
  const float* sr = s + (size_t)row * CS;
  float x[6];
  float sum = 0.f, sq = 0.f;
#pragma unroll
  for (int t = 0; t < 6; ++t) { x[t] = sr[lane + 64*t]; sum += x[t]; sq += x[t]*x[t]; }
#pragma unroll
  for (int off = 32; off; off >>= 1) { sum += __shfl_down(sum, off); sq += __shfl_down(sq, off); }
  sum = __shfl(sum, 0); sq = __shfl(sq, 0);
  float mean = sum * (1.f/CS);
  float var  = sq  * (1.f/CS) - mean*mean;
  float rstd = rsqrtf(var + 1e-5f);
  u16* orow = s_ln_bf + (size_t)row * CS;
#pragma unroll
  for (int t = 0; t < 6; ++t) orow[lane + 64*t] = f2bf((x[t]-mean)*rstd);
}

// ---------------------------------------------------------------------------
// LN(a=q fp32) + adaLN modulation, bf16 outs.  Used only for iteration 0.
// ---------------------------------------------------------------------------
__global__ __launch_bounds__(256) void modln_kernel(const float* __restrict__ a,
                                                    const u16* __restrict__ sp0,
                                                    const u16* __restrict__ sp1,
                                                    const u16* __restrict__ sp3,
                                                    const u16* __restrict__ sp4,
                                                    u16* __restrict__ amod,
                                                    u16* __restrict__ tmod) {
  int row  = blockIdx.x * 4 + (threadIdx.x >> 6);
  int lane = threadIdx.x & 63;
  const float* ar = a + (size_t)row * CA;
  float x0 = ar[lane], x1 = ar[lane + 64];
  float sum = x0 + x1, sq = x0*x0 + x1*x1;
#pragma unroll
  for (int off = 32; off; off >>= 1) { sum += __shfl_down(sum, off); sq += __shfl_down(sq, off); }
  sum = __shfl(sum, 0); sq = __shfl(sq, 0);
  float mean = sum * (1.f/CA);
  float var  = sq  * (1.f/CA) - mean*mean;
  float rstd = rsqrtf(var + 1e-5f);
  float n0 = (x0-mean)*rstd, n1 = (x1-mean)*rstd;
  size_t i0 = (size_t)row * CA + lane;
  amod[i0]      = f2bf(bf2f(sp0[i0])     *n0 + bf2f(sp1[i0]));
  amod[i0 + 64] = f2bf(bf2f(sp0[i0 + 64])*n1 + bf2f(sp1[i0 + 64]));
  tmod[i0]      = f2bf(bf2f(sp3[i0])     *n0 + bf2f(sp4[i0]));
  tmod[i0 + 64] = f2bf(bf2f(sp3[i0 + 64])*n1 + bf2f(sp4[i0 + 64]));
}

// ---------------------------------------------------------------------------
// Weight transpose+convert: src fp32 K x N (row-major)  ->  dst bf16 N x K.
// ---------------------------------------------------------------------------
struct TJob { const float* src; u16* dst; int K; int N; };
struct TJobs { TJob j[42]; };

__global__ __launch_bounds__(256) void transpose_bf16(TJobs jobs) {
  TJob jb = jobs.j[blockIdx.z];
  int tk = blockIdx.x * 32, tn = blockIdx.y * 32;
  if (tk >= jb.K || tn >= jb.N) return;
  __shared__ float tile[32][33];
  int tx = threadIdx.x & 31;
  int ty = threadIdx.x >> 5;
#pragma unroll
  for (int r = ty; r < 32; r += 8) tile[r][tx] = jb.src[(size_t)(tk + r) * jb.N + tn + tx];
  __syncthreads();
#pragma unroll
  for (int r = ty; r < 32; r += 8)
    jb.dst[(size_t)(tn + r) * jb.K + tk + tx] = f2bf(tile[tx][r]);
}

// ---------------------------------------------------------------------------
// bf16 MFMA GEMM, m97-style: global_load_lds(16B) staging, plain [m][k] LDS
// tile (128x32 bf16 = 8KB per operand).  128x128 block tile, 4 waves 2x2.
// modes: 0 = (+bias)->bf16, 1 = sigmoid(+bias)->bf16,
// 4 (DUAL) = silu(A@B)*(A@B2) -> bf16, 5 = transposed bf16 write (V).
// ---------------------------------------------------------------------------
struct GemmJob {
  const u16* A;
  const u16* Bt;
  const u16* Bt2;
  const float* bias;
  u16* outbf;
  int K;
  int ostride;
  int mode;
  int pad;
};
struct GemmJobs { GemmJob j[18]; };

template <bool DUAL>
__global__ __launch_bounds__(256) void gemm_mfma(GemmJobs jobs) {
  GemmJob jb = jobs.j[blockIdx.z];
  const int bm = blockIdx.y * 128, bn = blockIdx.x * 128;
  const int K = jb.K;

  __shared__ __attribute__((aligned(16))) u16 As[4096];
  __shared__ __attribute__((aligned(16))) u16 Bs[4096];
  __shared__ __attribute__((aligned(16))) u16 Bs2[DUAL ? 4096 : 8];

  const int tid  = threadIdx.x;
  const int lane = tid & 63;
  const int wave = tid >> 6;
  const int wr = wave >> 1, wc = wave & 1;
  const int l15 = lane & 15, quad = lane >> 4;

  floatx4 acc[4][4] = {};
  floatx4 acc2[DUAL ? 4 : 1][DUAL ? 4 : 1] = {};

  for (int k0 = 0; k0 < K; k0 += 32) {
    __syncthreads();
#pragma unroll
    for (int h = 0; h < 2; ++h) {
      int f = tid + 256 * h;
      int m = f >> 2, c = (f & 3) * 8;
      int lbase = (wave * 64 + 256 * h) * 8;
      gload16(jb.A  + (size_t)(bm + m) * K + k0 + c, As + lbase);
      gload16(jb.Bt + (size_t)(bn + m) * K + k0 + c, Bs + lbase);
      if constexpr (DUAL)
        gload16(jb.Bt2 + (size_t)(bn + m) * K + k0 + c, Bs2 + lbase);
    }
    __syncthreads();

    short8 a_frag[4], b_frag[4];
#pragma unroll
    for (int mt = 0; mt < 4; ++mt)
      a_frag[mt] = *(const short8*)(As + (wr * 64 + mt * 16 + l15) * 32 + quad * 8);
#pragma unroll
    for (int nt = 0; nt < 4; ++nt)
      b_frag[nt] = *(const short8*)(Bs + (wc * 64 + nt * 16 + l15) * 32 + quad * 8);
#pragma unroll
    for (int mt = 0; mt < 4; ++mt)
#pragma unroll
      for (int nt = 0; nt < 4; ++nt)
        acc[mt][nt] = __builtin_amdgcn_mfma_f32_16x16x32_bf16(a_frag[mt], b_frag[nt], acc[mt][nt], 0, 0, 0);
    if constexpr (DUAL) {
      short8 b2_frag[4];
#pragma unroll
      for (int nt = 0; nt < 4; ++nt)
        b2_frag[nt] = *(const short8*)(Bs2 + (wc * 64 + nt * 16 + l15) * 32 + quad * 8);
#pragma unroll
      for (int mt = 0; mt < 4; ++mt)
#pragma unroll
        for (int nt = 0; nt < 4; ++nt)
          acc2[mt][nt] = __builtin_amdgcn_mfma_f32_16x16x32_bf16(a_frag[mt], b2_frag[nt], acc2[mt][nt], 0, 0, 0);
    }
  }

  // Epilogue.  C/D layout: col = lane&15, row = quad*4 + reg.
#pragma unroll
  for (int mt = 0; mt < 4; ++mt) {
#pragma unroll
    for (int nt = 0; nt < 4; ++nt) {
      int n = bn + wc * 64 + nt * 16 + l15;
      int mbase = bm + wr * 64 + mt * 16 + quad * 4;
      floatx4 v = acc[mt][nt];
      if constexpr (DUAL) {
        floatx4 v2 = acc2[mt][nt];
#pragma unroll
        for (int r = 0; r < 4; ++r) {
          size_t idx = (size_t)(mbase + r) * jb.ostride + n;
          float x1 = v[r];
          jb.outbf[idx] = f2bf(x1 * sigmoidf_(x1) * v2[r]);
        }
      } else if (jb.mode == 5) {
        int bidx = mbase >> 13;          // m / NN
        int tok  = mbase & (NN - 1);
        ushort4 o;
        o.x = f2bf(v[0]); o.y = f2bf(v[1]); o.z = f2bf(v[2]); o.w = f2bf(v[3]);
        *(ushort4*)(jb.outbf + (size_t)(bidx * CA + n) * NN + tok) = o;
      } else {
        float bias = jb.bias ? jb.bias[n] : 0.f;
#pragma unroll
        for (int r = 0; r < 4; ++r) {
          size_t idx = (size_t)(mbase + r) * jb.ostride + n;
          float x = v[r] + bias;
          jb.outbf[idx] = f2bf(jb.mode == 1 ? sigmoidf_(x) : x);
        }
      }
    }
  }
}

// ---------------------------------------------------------------------------
// Combo output kernel: x = (O @ woT)*g1 + (HID @ twoT)*g2 (fp32 in regs).
// FINAL: write x fp32.  !FINAL: row-LayerNorm x in-block, then write
// amod = sig(sp0)*nx + sp1 and tmod likewise for the NEXT iteration.
// ---------------------------------------------------------------------------
template <bool FINAL>
__global__ __launch_bounds__(256) void combo_kernel(const u16* __restrict__ O,
                                                    const u16* __restrict__ HID,
                                                    const u16* __restrict__ woT,
                                                    const u16* __restrict__ twoT,
                                                    const u16* __restrict__ g1,
                                                    const u16* __restrict__ g2,
                                                    const u16* __restrict__ sp0,
                                                    const u16* __restrict__ sp1,
                                                    const u16* __restrict__ sp3,
                                                    const u16* __restrict__ sp4,
                                                    u16* __restrict__ amod,
                                                    u16* __restrict__ tmod,
                                                    float* __restrict__ outp) {
  const int bm = blockIdx.y * 128;
  __shared__ __attribute__((aligned(16))) u16 As[4096];
  __shared__ __attribute__((aligned(16))) u16 Bs[4096];
  __shared__ float redS[2][128];
  __shared__ float redQ[2][128];
  __shared__ float stats[128][2];
  const int tid  = threadIdx.x;
  const int lane = tid & 63;
  const int wave = tid >> 6;
  const int wr = wave >> 1, wc = wave & 1;
  const int l15 = lane & 15, quad = lane >> 4;

  floatx4 acc1[4][4] = {};
  floatx4 acc2[4][4] = {};

  // pass 1: K=128 over O/woT
  for (int k0 = 0; k0 < CA; k0 += 32) {
    __syncthreads();
#pragma unroll
    for (int h = 0; h < 2; ++h) {
      int f = tid + 256 * h;
      int m = f >> 2, c = (f & 3) * 8;
      int lbase = (wave * 64 + 256 * h) * 8;
      gload16(O   + (size_t)(bm + m) * CA + k0 + c, As + lbase);
      gload16(woT + (size_t)m * CA + k0 + c, Bs + lbase);
    }
    __syncthreads();
    short8 a_frag[4], b_frag[4];
#pragma unroll
    for (int mt = 0; mt < 4; ++mt)
      a_frag[mt] = *(const short8*)(As + (wr * 64 + mt * 16 + l15) * 32 + quad * 8);
#pragma unroll
    for (int nt = 0; nt < 4; ++nt)
      b_frag[nt] = *(const short8*)(Bs + (wc * 64 + nt * 16 + l15) * 32 + quad * 8);
#pragma unroll
    for (int mt = 0; mt < 4; ++mt)
#pragma unroll
      for (int nt = 0; nt < 4; ++nt)
        acc1[mt][nt] = __builtin_amdgcn_mfma_f32_16x16x32_bf16(a_frag[mt], b_frag[nt], acc1[mt][nt], 0, 0, 0);
  }
  // pass 2: K=256 over HID/twoT
  for (int k0 = 0; k0 < HIDN; k0 += 32) {
    __syncthreads();
#pragma unroll
    for (int h = 0; h < 2; ++h) {
      int f = tid + 256 * h;
      int m = f >> 2, c = (f & 3) * 8;
      int lbase = (wave * 64 + 256 * h) * 8;
      gload16(HID  + (size_t)(bm + m) * HIDN + k0 + c, As + lbase);
      gload16(twoT + (size_t)m * HIDN + k0 + c, Bs + lbase);
    }
    __syncthreads();
    short8 a_frag[4], b_frag[4];
#pragma unroll
    for (int mt = 0; mt < 4; ++mt)
      a_frag[mt] = *(const short8*)(As + (wr * 64 + mt * 16 + l15) * 32 + quad * 8);
#pragma unroll
    for (int nt = 0; nt < 4; ++nt)
      b_frag[nt] = *(const short8*)(Bs + (wc * 64 + nt * 16 + l15) * 32 + quad * 8);
#pragma unroll
    for (int mt = 0; mt < 4; ++mt)
#pragma unroll
      for (int nt = 0; nt < 4; ++nt)
        acc2[mt][nt] = __builtin_amdgcn_mfma_f32_16x16x32_bf16(a_frag[mt], b_frag[nt], acc2[mt][nt], 0, 0, 0);
  }

  // x = acc1*g1 + acc2*g2  (into acc1)
#pragma unroll
  for (int mt = 0; mt < 4; ++mt) {
#pragma unroll
    for (int nt = 0; nt < 4; ++nt) {
      int n = wc * 64 + nt * 16 + l15;
      int mbase = bm + wr * 64 + mt * 16 + quad * 4;
#pragma unroll
      for (int r = 0; r < 4; ++r) {
        size_t idx = (size_t)(mbase + r) * CA + n;
        acc1[mt][nt][r] = acc1[mt][nt][r] * bf2f(g1[idx]) + acc2[mt][nt][r] * bf2f(g2[idx]);
      }
    }
  }

  if constexpr (FINAL) {
#pragma unroll
    for (int mt = 0; mt < 4; ++mt)
#pragma unroll
      for (int nt = 0; nt < 4; ++nt) {
        int n = wc * 64 + nt * 16 + l15;
        int mbase = bm + wr * 64 + mt * 16 + quad * 4;
#pragma unroll
        for (int r = 0; r < 4; ++r)
          outp[(size_t)(mbase + r) * CA + n] = acc1[mt][nt][r];
      }
  } else {
    // row LayerNorm over 128 cols (2 waves share each row)
    float ps[4][4], pq[4][4];
#pragma unroll
    for (int mt = 0; mt < 4; ++mt)
#pragma unroll
      for (int r = 0; r < 4; ++r) {
        float s = 0.f, q2 = 0.f;
#pragma unroll
        for (int nt = 0; nt < 4; ++nt) { float v = acc1[mt][nt][r]; s += v; q2 += v*v; }
#pragma unroll
        for (int d = 1; d < 16; d <<= 1) { s += __shfl_xor(s, d); q2 += __shfl_xor(q2, d); }
        ps[mt][r] = s; pq[mt][r] = q2;
      }
    __syncthreads();   // As/Bs reads done; reuse of red arrays safe
    if (l15 == 0) {
#pragma unroll
      for (int mt = 0; mt < 4; ++mt)
#pragma unroll
        for (int r = 0; r < 4; ++r) {
          int row = wr * 64 + mt * 16 + quad * 4 + r;
          redS[wc][row] = ps[mt][r];
          redQ[wc][row] = pq[mt][r];
        }
    }
    __syncthreads();
    if (tid < 128) {
      float s  = redS[0][tid] + redS[1][tid];
      float q2 = redQ[0][tid] + redQ[1][tid];
      float mean = s * (1.f/CA);
      float var  = q2 * (1.f/CA) - mean*mean;
      stats[tid][0] = mean;
      stats[tid][1] = rsqrtf(var + 1e-5f);
    }
    __syncthreads();
#pragma unroll
    for (int mt = 0; mt < 4; ++mt)
#pragma unroll
      for (int nt = 0; nt < 4; ++nt) {
        int n = wc * 64 + nt * 16 + l15;
        int rowb = wr * 64 + mt * 16 + quad * 4;
#pragma unroll
        for (int r = 0; r < 4; ++r) {
          float mean = stats[rowb + r][0], rstd = stats[rowb + r][1];
          float nx = (acc1[mt][nt][r] - mean) * rstd;
          size_t idx = (size_t)(bm + rowb + r) * CA + n;
          amod[idx] = f2bf(bf2f(sp0[idx]) * nx + bf2f(sp1[idx]));
          tmod[idx] = f2bf(bf2f(sp3[idx]) * nx + bf2f(sp4[idx]));
        }
      }
  }
}

// ---------------------------------------------------------------------------
// Pair bias for ALL 3 blocks in one pass over p; direct ushort4 stores.
// Grid (4 k-chunks, W, B).  Output: biasT[i][b][w][h][k][q] (bf16).
// ---------------------------------------------------------------------------
__global__ __launch_bounds__(256) void bias3_kernel(const float* __restrict__ p,
                                                    const float* __restrict__ lnz_w,
                                                    const float* __restrict__ lnz_b,
                                                    const float* __restrict__ wb,
                                                    u16* __restrict__ biasT) {
  const int kc = blockIdx.x, w = blockIdx.y, b = blockIdx.z;
  __shared__ float effW[12][16];
  __shared__ float effb[12];
  const int t = threadIdx.x;
  if (t < 192) {
    int i = t >> 6, rem = t & 63, z = rem >> 2, hh = rem & 3;
    effW[i*4 + hh][z] = lnz_w[i*CZ + z] * wb[(i*CZ + z)*HH + hh];
  }
  if (t < 12) {
    int i = t >> 2, hh = t & 3;
    float acc = 0.f;
    for (int z = 0; z < 16; ++z) acc += lnz_b[i*CZ + z] * wb[(i*CZ + z)*HH + hh];
    effb[t] = acc;
  }
  __syncthreads();

  const int kk = t & 31, qg = (t >> 5) * 4;
  const int k = kc * 32 + kk;
  u16 out4[12][4];
#pragma unroll
  for (int r = 0; r < 4; ++r) {
    int qq = qg + r;
    const float4* pr = (const float4*)(p + (size_t)(((b * WW + w) * NQW + qq) * NKW + k) * 16);
    float4 p0 = pr[0], p1 = pr[1], p2 = pr[2], p3 = pr[3];
    float x[16] = {p0.x,p0.y,p0.z,p0.w, p1.x,p1.y,p1.z,p1.w,
                   p2.x,p2.y,p2.z,p2.w, p3.x,p3.y,p3.z,p3.w};
    float sum = 0.f, sq = 0.f;
#pragma unroll
    for (int z = 0; z < 16; ++z) { sum += x[z]; sq += x[z]*x[z]; }
    float mean = sum * (1.f/16.f);
    float var  = sq  * (1.f/16.f) - mean*mean;
    float rstd = rsqrtf(var + 1e-5f);
#pragma unroll
    for (int ih = 0; ih < 12; ++ih) {
      float acc = effb[ih];
#pragma unroll
      for (int z = 0; z < 16; ++z) acc += (x[z]-mean)*rstd * effW[ih][z];
      out4[ih][r] = f2bf(acc);
    }
  }
#pragma unroll
  for (int ih = 0; ih < 12; ++ih) {
    int i = ih >> 2, hh = ih & 3;
    u16* dst = biasT + ((((size_t)i * BB + b) * WW + w) * HH + hh) * 4096 + (size_t)k * 32 + qg;
    ushort4 uv; uv.x = out4[ih][0]; uv.y = out4[ih][1]; uv.z = out4[ih][2]; uv.w = out4[ih][3];
    *(ushort4*)dst = uv;
  }
}

// ---------------------------------------------------------------------------
// MFMA windowed attention: one WAVE per (w, h, b).
// ---------------------------------------------------------------------------
__global__ __launch_bounds__(64) void attn_mfma(const u16* __restrict__ Qb,
                                                const u16* __restrict__ Kb,
                                                const u16* __restrict__ Vtb,
                                                const u16* __restrict__ Gb,
                                                const u16* __restrict__ biasT,
                                                u16* __restrict__ Ob) {
  const int w = blockIdx.x, h = blockIdx.y, b = blockIdx.z;
  __shared__ u16 Pt[128 * 36];
  __shared__ float inv_s[32];
  const int lane = threadIdx.x;
  const int l15 = lane & 15, quad = lane >> 4;
  const int tok0 = w * NQW - 48;

  short8 qf[2];
#pragma unroll
  for (int mt = 0; mt < 2; ++mt) {
    int qq = w * NQW + mt * 16 + l15;
    qf[mt] = *(const short8*)(Qb + (size_t)(b * NN + qq) * CA + h * DD + quad * 8);
  }
  floatx4 lg[2][8] = {};
#pragma unroll
  for (int nt = 0; nt < 8; ++nt) {
    int tk = tok0 + nt * 16 + l15;
    int tc = min(max(tk, 0), NN - 1);
    short8 kf = *(const short8*)(Kb + (size_t)(b * NN + tc) * CA + h * DD + quad * 8);
#pragma unroll
    for (int mt = 0; mt < 2; ++mt)
      lg[mt][nt] = __builtin_amdgcn_mfma_f32_16x16x32_bf16(qf[mt], kf, lg[mt][nt], 0, 0, 0);
  }

  const float scale = 0.17677669529663687f;   // 1/sqrt(32)
  const u16* bb = biasT + ((((size_t)b * WW + w) * HH + h) << 12);
  float mrow[2][4];
#pragma unroll
  for (int mt = 0; mt < 2; ++mt)
#pragma unroll
    for (int r = 0; r < 4; ++r) mrow[mt][r] = -3.0e38f;
#pragma unroll
  for (int nt = 0; nt < 8; ++nt) {
    int tk = tok0 + nt * 16 + l15;
    bool valid = (tk >= 0) && (tk < NN);
#pragma unroll
    for (int mt = 0; mt < 2; ++mt) {
      ushort4 bv = *(const ushort4*)(bb + (nt * 16 + l15) * 32 + mt * 16 + quad * 4);
      float bvf[4] = {bf2f(bv.x), bf2f(bv.y), bf2f(bv.z), bf2f(bv.w)};
#pragma unroll
      for (int r = 0; r < 4; ++r) {
        float l = valid ? (lg[mt][nt][r] * scale + bvf[r]) : -1e9f;
        lg[mt][nt][r] = l;
        mrow[mt][r] = fmaxf(mrow[mt][r], l);
      }
    }
  }
#pragma unroll
  for (int mt = 0; mt < 2; ++mt)
#pragma unroll
    for (int r = 0; r < 4; ++r) {
      float m = mrow[mt][r];
      m = fmaxf(m, __shfl_xor(m, 1));
      m = fmaxf(m, __shfl_xor(m, 2));
      m = fmaxf(m, __shfl_xor(m, 4));
      m = fmaxf(m, __shfl_xor(m, 8));
      mrow[mt][r] = m;
    }

  float srow[2][4] = {};
#pragma unroll
  for (int nt = 0; nt < 8; ++nt)
#pragma unroll
    for (int mt = 0; mt < 2; ++mt) {
      u16 pv[4];
#pragma unroll
      for (int r = 0; r < 4; ++r) {
        float e = __expf(lg[mt][nt][r] - mrow[mt][r]);
        srow[mt][r] += e;
        pv[r] = f2bf(e);
      }
      ushort4 uv; uv.x = pv[0]; uv.y = pv[1]; uv.z = pv[2]; uv.w = pv[3];
      *(ushort4*)(Pt + (nt * 16 + l15) * 36 + mt * 16 + quad * 4) = uv;
    }
#pragma unroll
  for (int mt = 0; mt < 2; ++mt)
#pragma unroll
    for (int r = 0; r < 4; ++r) {
      float ssum = srow[mt][r];
      ssum += __shfl_xor(ssum, 1);
      ssum += __shfl_xor(ssum, 2);
      ssum += __shfl_xor(ssum, 4);
      ssum += __shfl_xor(ssum, 8);
      if (l15 == 0) inv_s[mt * 16 + quad * 4 + r] = 1.f / ssum;
    }
  __syncthreads();

  floatx4 oacc[2][2] = {};
#pragma unroll
  for (int ks = 0; ks < 4; ++ks) {
    short8 pf[2];
#pragma unroll
    for (int ntq = 0; ntq < 2; ++ntq)
#pragma unroll
      for (int j = 0; j < 8; ++j)
        pf[ntq][j] = (short)Pt[(ks * 32 + quad * 8 + j) * 36 + ntq * 16 + l15];
    int tb = tok0 + ks * 32 + quad * 8;
    tb = min(max(tb, 0), NN - 8);
#pragma unroll
    for (int mtd = 0; mtd < 2; ++mtd) {
      short8 vf = *(const short8*)(Vtb + (size_t)(b * CA + h * DD + mtd * 16 + l15) * NN + tb);
#pragma unroll
      for (int ntq = 0; ntq < 2; ++ntq)
        oacc[mtd][ntq] = __builtin_amdgcn_mfma_f32_16x16x32_bf16(vf, pf[ntq], oacc[mtd][ntq], 0, 0, 0);
    }
  }

#pragma unroll
  for (int mtd = 0; mtd < 2; ++mtd)
#pragma unroll
    for (int ntq = 0; ntq < 2; ++ntq) {
      int qq = ntq * 16 + l15;
      float inv = inv_s[qq];
      int tok = w * NQW + qq;
      size_t base = (size_t)(b * NN + tok) * CA + h * DD + mtd * 16 + quad * 4;
      ushort4 gv = *(const ushort4*)(Gb + base);
      floatx4 v = oacc[mtd][ntq];
      ushort4 o;
      o.x = f2bf(bf2f(gv.x) * v[0] * inv);
      o.y = f2bf(bf2f(gv.y) * v[1] * inv);
      o.z = f2bf(bf2f(gv.z) * v[2] * inv);
      o.w = f2bf(bf2f(gv.w) * v[3] * inv);
      *(ushort4*)(Ob + base) = o;
    }
}

// ---------------------------------------------------------------------------
// Host-side orchestration.
// ---------------------------------------------------------------------------
extern "C" void kernel_launch(void* const* d_in, const int* in_sizes, int n_in,
                              void* d_out, int out_size, void* d_ws, size_t ws_size,
                              hipStream_t stream) {
  const float* q             = (const float*)d_in[0];
  const float* s             = (const float*)d_in[1];
  const float* p             = (const float*)d_in[2];
  const float* adaln_scale_w = (const float*)d_in[3];
  const float* adaln_scale_b = (const float*)d_in[4];
  const float* adaln_shift_w = (const float*)d_in[5];
  const float* wq            = (const float*)d_in[6];
  const float* bq            = (const float*)d_in[7];
  const float* wk            = (const float*)d_in[8];
  const float* wv            = (const float*)d_in[9];
  const float* lnz_w         = (const float*)d_in[10];
  const float* lnz_b         = (const float*)d_in[11];
  const float* wb_pair       = (const float*)d_in[12];
  const float* wg            = (const float*)d_in[13];
  const float* wo            = (const float*)d_in[14];
  const float* sgate_w       = (const float*)d_in[15];
  const float* sgate_b       = (const float*)d_in[16];
  const float* t_scale_w     = (const float*)d_in[17];
  const float* t_scale_b     = (const float*)d_in[18];
  const float* t_shift_w     = (const float*)d_in[19];
  const float* t_wa          = (const float*)d_in[20];
  const float* t_wb          = (const float*)d_in[21];
  const float* t_wo          = (const float*)d_in[22];
  const float* t_sgate_w     = (const float*)d_in[23];
  const float* t_sgate_b     = (const float*)d_in[24];
  float* out = (float*)d_out;

  const size_t MC = (size_t)MR * CA; // 2097152
  u16* uws     = (u16*)d_ws;
  u16* s_ln_bf = uws;                          // MR*CS
  u16* SP      = s_ln_bf + (size_t)MR * CS;    // 18*MC
  u16* amod    = SP + 18*MC;
  u16* tmod    = amod + MC;
  u16* Qb      = tmod + MC;
  u16* Kb      = Qb + MC;
  u16* Vtb     = Kb + MC;                      // [b][128][NN]
  u16* Gb      = Vtb + MC;
  u16* Ob      = Gb + MC;
  u16* HIDb    = Ob + MC;                      // MR*HIDN = 2*MC
  u16* biasT   = HIDb + 2*MC;                  // 3*BB*WW*HH*4096
  u16* wbuf    = biasT + (size_t)3*BB*WW*HH*NQW*NKW;

  const size_t WBLK = 6*(size_t)CA*CS + 5*(size_t)CA*CA + 3*(size_t)CA*HIDN;
  const size_t o_ascale = 0;
  const size_t o_ashift = o_ascale + (size_t)CA*CS;
  const size_t o_sgate  = o_ashift + (size_t)CA*CS;
  const size_t o_tscale = o_sgate  + (size_t)CA*CS;
  const size_t o_tshift = o_tscale + (size_t)CA*CS;
  const size_t o_tsgate = o_tshift + (size_t)CA*CS;
  const size_t o_wq     = o_tsgate + (size_t)CA*CS;
  const size_t o_wk     = o_wq + (size_t)CA*CA;
  const size_t o_wv     = o_wk + (size_t)CA*CA;
  const size_t o_wg     = o_wv + (size_t)CA*CA;
  const size_t o_wo     = o_wg + (size_t)CA*CA;
  const size_t o_twa    = o_wo + (size_t)CA*CA;
  const size_t o_twb    = o_twa + (size_t)HIDN*CA;
  const size_t o_two    = o_twb + (size_t)HIDN*CA;

  // ---- one-time work ----
  ln_s_kernel<<<MR/4, 256, 0, stream>>>(s, s_ln_bf);

  TJobs tj;
  for (int i = 0; i < NBLK; ++i) {
    u16* wb0 = wbuf + (size_t)i * WBLK;
    int b14 = i * 14;
    tj.j[b14+0]  = TJob{adaln_scale_w + (size_t)i*CS*CA, wb0 + o_ascale, CS, CA};
    tj.j[b14+1]  = TJob{adaln_shift_w + (size_t)i*CS*CA, wb0 + o_ashift, CS, CA};
    tj.j[b14+2]  = TJob{sgate_w       + (size_t)i*CS*CA, wb0 + o_sgate,  CS, CA};
    tj.j[b14+3]  = TJob{t_scale_w     + (size_t)i*CS*CA, wb0 + o_tscale, CS, CA};
    tj.j[b14+4]  = TJob{t_shift_w     + (size_t)i*CS*CA, wb0 + o_tshift, CS, CA};
    tj.j[b14+5]  = TJob{t_sgate_w     + (size_t)i*CS*CA, wb0 + o_tsgate, CS, CA};
    tj.j[b14+6]  = TJob{wq   + (size_t)i*CA*CA,   wb0 + o_wq,  CA, CA};
    tj.j[b14+7]  = TJob{wk   + (size_t)i*CA*CA,   wb0 + o_wk,  CA, CA};
    tj.j[b14+8]  = TJob{wv   + (size_t)i*CA*CA,   wb0 + o_wv,  CA, CA};
    tj.j[b14+9]  = TJob{wg   + (size_t)i*CA*CA,   wb0 + o_wg,  CA, CA};
    tj.j[b14+10] = TJob{wo   + (size_t)i*CA*CA,   wb0 + o_wo,  CA, CA};
    tj.j[b14+11] = TJob{t_wa + (size_t)i*CA*HIDN, wb0 + o_twa, CA, HIDN};
    tj.j[b14+12] = TJob{t_wb + (size_t)i*CA*HIDN, wb0 + o_twb, CA, HIDN};
    tj.j[b14+13] = TJob{t_wo + (size_t)i*HIDN*CA, wb0 + o_two, HIDN, CA};
  }
  transpose_bf16<<<dim3(12, 8, 42), 256, 0, stream>>>(tj);

  bias3_kernel<<<dim3(4, WW, BB), 256, 0, stream>>>(p, lnz_w, lnz_b, wb_pair, biasT);

  // ALL 18 s_ln projections (iteration-invariant) in one launch
  {
    GemmJobs js = {};
    for (int i = 0; i < NBLK; ++i) {
      u16* wb0 = wbuf + (size_t)i * WBLK;
      js.j[i*6+0] = GemmJob{s_ln_bf, wb0 + o_ascale, nullptr, adaln_scale_b + i*CA, SP + (i*6+0)*MC, CS, CA, 1, 0};
      js.j[i*6+1] = GemmJob{s_ln_bf, wb0 + o_ashift, nullptr, nullptr,              SP + (i*6+1)*MC, CS, CA, 0, 0};
      js.j[i*6+2] = GemmJob{s_ln_bf, wb0 + o_sgate,  nullptr, sgate_b   + i*CA,     SP + (i*6+2)*MC, CS, CA, 1, 0};
      js.j[i*6+3] = GemmJob{s_ln_bf, wb0 + o_tscale, nullptr, t_scale_b + i*CA,     SP + (i*6+3)*MC, CS, CA, 1, 0};
      js.j[i*6+4] = GemmJob{s_ln_bf, wb0 + o_tshift, nullptr, nullptr,              SP + (i*6+4)*MC, CS, CA, 0, 0};
      js.j[i*6+5] = GemmJob{s_ln_bf, wb0 + o_tsgate, nullptr, t_sgate_b + i*CA,     SP + (i*6+5)*MC, CS, CA, 1, 0};
    }
    gemm_mfma<false><<<dim3(1, MR/128, 18), 256, 0, stream>>>(js);
  }

  // iteration 0 modulation from a = q
  modln_kernel<<<MR/4, 256, 0, stream>>>(q, SP + 0*MC, SP + 1*MC, SP + 3*MC, SP + 4*MC,
                                         amod, tmod);

  for (int i = 0; i < NBLK; ++i) {
    u16* wb0 = wbuf + (size_t)i * WBLK;

    // Q, K, V(transposed), G projections -> bf16
    GemmJobs jq = {};
    jq.j[0] = GemmJob{amod, wb0 + o_wq, nullptr, bq + i*CA, Qb,  CA, CA, 0, 0};
    jq.j[1] = GemmJob{amod, wb0 + o_wk, nullptr, nullptr,   Kb,  CA, CA, 0, 0};
    jq.j[2] = GemmJob{amod, wb0 + o_wv, nullptr, nullptr,   Vtb, CA, CA, 5, 0};
    jq.j[3] = GemmJob{amod, wb0 + o_wg, nullptr, nullptr,   Gb,  CA, CA, 1, 0};
    gemm_mfma<false><<<dim3(1, MR/128, 4), 256, 0, stream>>>(jq);

    // hidden = silu(tmod @ t_wa) * (tmod @ t_wb)  -> bf16 (N=256)
    GemmJobs jh = {};
    jh.j[0] = GemmJob{tmod, wb0 + o_twa, wb0 + o_twb, nullptr, HIDb, CA, HIDN, 4, 0};
    gemm_mfma<true><<<dim3(2, MR/128, 1), 256, 0, stream>>>(jh);

    // windowed attention (MFMA, g-gated bf16 out)
    attn_mfma<<<dim3(WW, HH, BB), 64, 0, stream>>>(
        Qb, Kb, Vtb, Gb, biasT + (size_t)i * BB*WW*HH*4096, Ob);

    // x = (O@wo)*sgate + (HID@two)*tsgate ; i<2: fused LN + next modulation
    if (i < 2) {
      combo_kernel<false><<<dim3(1, MR/128), 256, 0, stream>>>(
          Ob, HIDb, wb0 + o_wo, wb0 + o_two,
          SP + (i*6+2)*MC, SP + (i*6+5)*MC,
          SP + ((i+1)*6+0)*MC, SP + ((i+1)*6+1)*MC,
          SP + ((i+1)*6+3)*MC, SP + ((i+1)*6+4)*MC,
          amod, tmod, nullptr);
    } else {
      combo_kernel<true><<<dim3(1, MR/128), 256, 0, stream>>>(
          Ob, HIDb, wb0 + o_wo, wb0 + o_two,
          SP + (i*6+2)*MC, SP + (i*6+5)*MC,
          nullptr, nullptr, nullptr, nullptr,
          nullptr, nullptr, out);
    }
  }
}